// Round 1
// baseline (890.959 us; speedup 1.0000x reference)
//
#include <hip/hip_runtime.h>
#include <hip/hip_bf16.h>
#include <cstdint>
#include <cstddef>

typedef __bf16 bf16_t;
typedef __bf16 bf16x8 __attribute__((ext_vector_type(8)));
typedef __bf16 bf16x4 __attribute__((ext_vector_type(4)));
typedef float  f32x4  __attribute__((ext_vector_type(4)));

#define DEV __device__ __forceinline__

DEV void gload16(void* lds, const void* gmem) {
  __builtin_amdgcn_global_load_lds(
      (const __attribute__((address_space(1))) void*)gmem,
      (__attribute__((address_space(3))) void*)lds, 16, 0, 0);
}

DEV f32x4 mfma16(bf16x8 a, bf16x8 b, f32x4 c) {
  return __builtin_amdgcn_mfma_f32_16x16x32_bf16(a, b, c, 0, 0, 0);
}

// ---------------------------------------------------------------------------
// Weight convert + transpose: src fp32 [K][N] -> dst bf16 [N][K]
// ---------------------------------------------------------------------------
__global__ __launch_bounds__(256)
void conv_t_kernel(const float* __restrict__ src, bf16_t* __restrict__ dst,
                   int K, int N) {
  __shared__ float tile[64][65];
  const int k0 = blockIdx.x * 64, n0 = blockIdx.y * 64;
  const int t = threadIdx.x;
#pragma unroll
  for (int c = 0; c < 16; c++) {
    int idx = c * 256 + t;
    int r = idx >> 6, cc = idx & 63;           // r: k-local, cc: n-local
    tile[r][cc] = src[(size_t)(k0 + r) * N + n0 + cc];
  }
  __syncthreads();
#pragma unroll
  for (int c = 0; c < 16; c++) {
    int idx = c * 256 + t;
    int r = idx >> 6, cc = idx & 63;           // r: n-local, cc: k-local
    dst[(size_t)(n0 + r) * K + k0 + cc] = (bf16_t)tile[cc][r];
  }
}

// ---------------------------------------------------------------------------
// LayerNorm over D=1024: out = (in*alpha + resid - mu)*rsqrt(var+eps)*g + b
// One block per row, 256 threads, 4 elements each.
// ---------------------------------------------------------------------------
__global__ __launch_bounds__(256)
void ln_kernel(const float* __restrict__ in, const float* __restrict__ resid,
               const float* __restrict__ g, const float* __restrict__ bt,
               float alpha, float* __restrict__ outf, bf16_t* __restrict__ outb) {
  const int row = blockIdx.x, t = threadIdx.x;
  const float4 vi = *(const float4*)(in + (size_t)row * 1024 + t * 4);
  float x0 = vi.x * alpha, x1 = vi.y * alpha, x2 = vi.z * alpha, x3 = vi.w * alpha;
  if (resid) {
    const float4 rv = *(const float4*)(resid + (size_t)row * 1024 + t * 4);
    x0 += rv.x; x1 += rv.y; x2 += rv.z; x3 += rv.w;
  }
  float s = x0 + x1 + x2 + x3;
  float sq = x0 * x0 + x1 * x1 + x2 * x2 + x3 * x3;
#pragma unroll
  for (int m = 1; m < 64; m <<= 1) { s += __shfl_xor(s, m); sq += __shfl_xor(sq, m); }
  __shared__ float ps[4], pq[4];
  const int wave = t >> 6;
  if ((t & 63) == 0) { ps[wave] = s; pq[wave] = sq; }
  __syncthreads();
  s = ps[0] + ps[1] + ps[2] + ps[3];
  sq = pq[0] + pq[1] + pq[2] + pq[3];
  const float mu = s * (1.0f / 1024.0f);
  const float var = sq * (1.0f / 1024.0f) - mu * mu;
  const float rs = rsqrtf(var + 1e-6f);
  const float4 gv = *(const float4*)(g + t * 4);
  const float4 bv = *(const float4*)(bt + t * 4);
  float y0 = (x0 - mu) * rs * gv.x + bv.x;
  float y1 = (x1 - mu) * rs * gv.y + bv.y;
  float y2 = (x2 - mu) * rs * gv.z + bv.z;
  float y3 = (x3 - mu) * rs * gv.w + bv.w;
  if (outf) *(float4*)(outf + (size_t)row * 1024 + t * 4) = make_float4(y0, y1, y2, y3);
  if (outb) {
    bf16x4 o; o[0] = (bf16_t)y0; o[1] = (bf16_t)y1; o[2] = (bf16_t)y2; o[3] = (bf16_t)y3;
    *(bf16x4*)(outb + (size_t)row * 1024 + t * 4) = o;
  }
}

// ---------------------------------------------------------------------------
// GEMM: C[2048][N] = A[2048][K] (bf16) @ Bt[N][K]^T (bf16), fp32 accum.
// BM=128, BN=64, BK=64, 256 threads (4 waves 2x2), double-buffered LDS,
// global_load_lds staging with XOR(row&7) 16B-slot swizzle.
// EPI: 0 = plain f32 out; 1 = +bias, relu, bf16 out; 2 = +bias, f32 out.
// ---------------------------------------------------------------------------
template <int EPI>
__global__ __launch_bounds__(256, 2)
void gemm_kernel(const bf16_t* __restrict__ A, const bf16_t* __restrict__ Bt,
                 const float* __restrict__ bias, float* __restrict__ Cf,
                 bf16_t* __restrict__ Cb, int N, int K) {
  constexpr int BM = 128, BN = 64, BK = 64;
  __shared__ __align__(16) bf16_t As[2][BM * BK];
  __shared__ __align__(16) bf16_t Bs[2][BN * BK];
  const int tid = threadIdx.x;
  const int wave = tid >> 6, lane = tid & 63;
  const int l16 = lane & 15, l4 = lane >> 4;
  const int m0 = blockIdx.x * BM, n0 = blockIdx.y * BN;
  const int wm = wave >> 1, wn = wave & 1;
  f32x4 acc[4][2] = {};

  const int nt = K / BK;
  auto stage = [&](int buf, int k0) {
#pragma unroll
    for (int c = 0; c < 4; c++) {
      int gidx = c * 256 + tid;
      int row = gidx >> 3, s = gidx & 7;
      gload16(&As[buf][(c * 256 + wave * 64) * 8],
              A + (size_t)(m0 + row) * K + k0 + ((s ^ (row & 7)) << 3));
    }
#pragma unroll
    for (int c = 0; c < 2; c++) {
      int gidx = c * 256 + tid;
      int row = gidx >> 3, s = gidx & 7;
      gload16(&Bs[buf][(c * 256 + wave * 64) * 8],
              Bt + (size_t)(n0 + row) * K + k0 + ((s ^ (row & 7)) << 3));
    }
  };

  stage(0, 0);
  __syncthreads();
  for (int t = 0; t < nt; t++) {
    const int cur = t & 1;
    if (t + 1 < nt) stage(cur ^ 1, (t + 1) * BK);
    const bf16_t* as = As[cur];
    const bf16_t* bs = Bs[cur];
#pragma unroll
    for (int kk = 0; kk < 2; kk++) {
      bf16x8 af[4], bfr[2];
#pragma unroll
      for (int m = 0; m < 4; m++) {
        int row = wm * 64 + m * 16 + l16;
        af[m] = *(const bf16x8*)(as + row * 64 + ((((kk << 2) + l4) ^ (row & 7)) << 3));
      }
#pragma unroll
      for (int n = 0; n < 2; n++) {
        int row = wn * 32 + n * 16 + l16;
        bfr[n] = *(const bf16x8*)(bs + row * 64 + ((((kk << 2) + l4) ^ (row & 7)) << 3));
      }
#pragma unroll
      for (int m = 0; m < 4; m++)
#pragma unroll
        for (int n = 0; n < 2; n++)
          acc[m][n] = mfma16(af[m], bfr[n], acc[m][n]);
    }
    __syncthreads();
  }

#pragma unroll
  for (int m = 0; m < 4; m++) {
#pragma unroll
    for (int n = 0; n < 2; n++) {
      int col = n0 + wn * 32 + n * 16 + l16;
      float bv = 0.0f;
      if (EPI != 0) bv = bias[col];
#pragma unroll
      for (int r = 0; r < 4; r++) {
        int row = m0 + wm * 64 + m * 16 + l4 * 4 + r;
        float v = acc[m][n][r] + bv;
        if (EPI == 1) {
          v = fmaxf(v, 0.0f);
          Cb[(size_t)row * N + col] = (bf16_t)v;
        } else {
          Cf[(size_t)row * N + col] = v;
        }
      }
    }
  }
}

// ---------------------------------------------------------------------------
// RoPE (head-indexed tables, pos = 1008+h) + 1/sqrt(DK) fold into Q.
// qkv fp32 [2048][3072] -> Qb,Kb bf16 [32][1024][64]
// ---------------------------------------------------------------------------
__global__ __launch_bounds__(256)
void rope_kernel(const float* __restrict__ qkv, bf16_t* __restrict__ Qb,
                 bf16_t* __restrict__ Kb) {
  const int m = blockIdx.x, t = threadIdx.x;
  const int h = t >> 4, i = t & 15;
  const int b = m >> 10, l = m & 1023;
  const float pos = (float)(1008 + h);
  const float ang = pos * exp2f(-0.75f * (float)i);
  float sn, cs;
  sincosf(ang, &sn, &cs);
  const float* q = qkv + (size_t)m * 3072 + h * 64;
  const float* k = q + 1024;
  const size_t ob = ((size_t)(b * 16 + h) * 1024 + l) * 64;
  const float it = 0.125f;  // 1/sqrt(64)
  float qi = q[i], qj = q[i + 16];
  Qb[ob + i]      = (bf16_t)((qi * cs - qj * sn) * it);
  Qb[ob + i + 16] = (bf16_t)((qj * cs + qi * sn) * it);
  Qb[ob + i + 32] = (bf16_t)(q[i + 32] * it);
  Qb[ob + i + 48] = (bf16_t)(q[i + 48] * it);
  float ki = k[i], kj = k[i + 16];
  Kb[ob + i]      = (bf16_t)(ki * cs - kj * sn);
  Kb[ob + i + 16] = (bf16_t)(kj * cs + ki * sn);
  Kb[ob + i + 32] = (bf16_t)k[i + 32];
  Kb[ob + i + 48] = (bf16_t)k[i + 48];
}

// ---------------------------------------------------------------------------
// V transpose: qkv fp32 [2048][3072] (v at col 2048+h*64+d) -> Vt bf16 [32][64][1024]
// ---------------------------------------------------------------------------
__global__ __launch_bounds__(256)
void vtrans_kernel(const float* __restrict__ qkv, bf16_t* __restrict__ Vt) {
  const int bh = blockIdx.x, lt = blockIdx.y;
  const int b = bh >> 4, h = bh & 15;
  __shared__ float tile[64][65];
  const int t = threadIdx.x;
#pragma unroll
  for (int c = 0; c < 16; c++) {
    int idx = c * 256 + t;
    int r = idx >> 6, d = idx & 63;            // r: l-local, d: dim
    tile[r][d] = qkv[(size_t)(b * 1024 + lt * 64 + r) * 3072 + 2048 + h * 64 + d];
  }
  __syncthreads();
#pragma unroll
  for (int c = 0; c < 16; c++) {
    int idx = c * 256 + t;
    int d = idx >> 6, r = idx & 63;            // d: dim, r: l-local
    Vt[((size_t)bh * 64 + d) * 1024 + lt * 64 + r] = (bf16_t)tile[r][d];
  }
}

// ---------------------------------------------------------------------------
// Attention: per (b,h) x 64-q-row block. 4 waves, 16 q-rows each.
// S = Q K^T via MFMA; online softmax in C-layout; P -> swizzled per-wave LDS
// tile -> A-operand; PV with V^T read straight from global.
// ---------------------------------------------------------------------------
__global__ __launch_bounds__(256, 2)
void attn_kernel(const bf16_t* __restrict__ Qb, const bf16_t* __restrict__ Kb,
                 const bf16_t* __restrict__ Vt, bf16_t* __restrict__ Ob) {
  const int bh = blockIdx.x;
  const int q0 = blockIdx.y * 64;
  const int wave = threadIdx.x >> 6, lane = threadIdx.x & 63;
  const int l16 = lane & 15, l4 = lane >> 4;
  const bf16_t* Q = Qb + (size_t)bh * 65536;
  const bf16_t* K = Kb + (size_t)bh * 65536;
  const bf16_t* V = Vt + (size_t)bh * 65536;
  __shared__ __align__(16) bf16_t Plds[4][16 * 64];
  bf16_t* pl = Plds[wave];

  const int qrow = q0 + wave * 16 + l16;
  const bf16x8 qf0 = *(const bf16x8*)(Q + (size_t)qrow * 64 + l4 * 8);
  const bf16x8 qf1 = *(const bf16x8*)(Q + (size_t)qrow * 64 + 32 + l4 * 8);

  f32x4 o[4] = {};
  float mrow[4] = {-1e30f, -1e30f, -1e30f, -1e30f};
  float lrow[4] = {0.f, 0.f, 0.f, 0.f};
  constexpr float L2E = 1.44269504088896340736f;

  for (int kt = 0; kt < 16; kt++) {
    const int j0 = kt * 64;
    f32x4 s[4] = {};
#pragma unroll
    for (int nf = 0; nf < 4; nf++) {
      const bf16_t* kp = K + (size_t)(j0 + nf * 16 + l16) * 64;
      bf16x8 k0 = *(const bf16x8*)(kp + l4 * 8);
      bf16x8 k1 = *(const bf16x8*)(kp + 32 + l4 * 8);
      s[nf] = mfma16(qf0, k0, s[nf]);
      s[nf] = mfma16(qf1, k1, s[nf]);
    }
#pragma unroll
    for (int r = 0; r < 4; r++) {
      float tm = fmaxf(fmaxf(s[0][r], s[1][r]), fmaxf(s[2][r], s[3][r]));
      tm = fmaxf(tm, __shfl_xor(tm, 1));
      tm = fmaxf(tm, __shfl_xor(tm, 2));
      tm = fmaxf(tm, __shfl_xor(tm, 4));
      tm = fmaxf(tm, __shfl_xor(tm, 8));
      const float mnew = fmaxf(mrow[r], tm);
      const float c = exp2f((mrow[r] - mnew) * L2E);
      mrow[r] = mnew;
      lrow[r] *= c;
      o[0][r] *= c; o[1][r] *= c; o[2][r] *= c; o[3][r] *= c;
      const int prow = l4 * 4 + r;
      const int rs = prow & 7;
#pragma unroll
      for (int nf = 0; nf < 4; nf++) {
        float p = exp2f((s[nf][r] - mnew) * L2E);
        lrow[r] += p;
        int gran = (nf << 1) + (l16 >> 3);
        pl[(prow << 6) + ((gran ^ rs) << 3) + (l16 & 7)] = (bf16_t)p;
      }
    }
    // PV: A = P (from LDS), B = V^T rows (global)
#pragma unroll
    for (int jc = 0; jc < 2; jc++) {
      const int prow = l16;
      bf16x8 pf = *(const bf16x8*)(pl + (prow << 6) +
                                   ((((jc << 2) + l4) ^ (prow & 7)) << 3));
#pragma unroll
      for (int df = 0; df < 4; df++) {
        bf16x8 vf = *(const bf16x8*)(V + (size_t)(df * 16 + l16) * 1024 + j0 +
                                     jc * 32 + l4 * 8);
        o[df] = mfma16(pf, vf, o[df]);
      }
    }
  }

  float inv[4];
#pragma unroll
  for (int r = 0; r < 4; r++) {
    float lr = lrow[r];
    lr += __shfl_xor(lr, 1);
    lr += __shfl_xor(lr, 2);
    lr += __shfl_xor(lr, 4);
    lr += __shfl_xor(lr, 8);
    inv[r] = 1.0f / lr;
  }
  const int b = bh >> 4, h = bh & 15;
#pragma unroll
  for (int df = 0; df < 4; df++) {
#pragma unroll
    for (int r = 0; r < 4; r++) {
      int rl = q0 + wave * 16 + l4 * 4 + r;
      Ob[((size_t)(b * 1024 + rl)) * 1024 + h * 64 + df * 16 + l16] =
          (bf16_t)(o[df][r] * inv[r]);
    }
  }
}

// ---------------------------------------------------------------------------
extern "C" void kernel_launch(void* const* d_in, const int* in_sizes, int n_in,
                              void* d_out, int out_size, void* d_ws, size_t ws_size,
                              hipStream_t stream) {
  (void)in_sizes; (void)n_in; (void)out_size;
  const float* src  = (const float*)d_in[0];
  const float* Wq   = (const float*)d_in[1];
  const float* Wk   = (const float*)d_in[2];
  const float* Wv   = (const float*)d_in[3];
  const float* Wo   = (const float*)d_in[4];
  const float* ln1g = (const float*)d_in[5];
  const float* ln1b = (const float*)d_in[6];
  const float* W1   = (const float*)d_in[7];
  const float* b1   = (const float*)d_in[8];
  const float* W2   = (const float*)d_in[9];
  const float* b2   = (const float*)d_in[10];
  const float* ln2g = (const float*)d_in[11];
  const float* ln2b = (const float*)d_in[12];
  const float* ln0g = (const float*)d_in[13];
  const float* ln0b = (const float*)d_in[14];

  char* ws = (char*)d_ws;
  size_t off = 0;
  auto alloc = [&](size_t bytes) -> char* {
    char* p = ws + off;
    off += (bytes + 255) & ~(size_t)255;
    return p;
  };
  bf16_t* wqkvt = (bf16_t*)alloc((size_t)3072 * 1024 * 2);
  bf16_t* wot   = (bf16_t*)alloc((size_t)1024 * 1024 * 2);
  bf16_t* w1t   = (bf16_t*)alloc((size_t)4096 * 1024 * 2);
  bf16_t* w2t   = (bf16_t*)alloc((size_t)1024 * 4096 * 2);
  float*  x     = (float*) alloc((size_t)2048 * 1024 * 4);
  bf16_t* xb    = (bf16_t*)alloc((size_t)2048 * 1024 * 2);
  float*  qkv   = (float*) alloc((size_t)2048 * 3072 * 4);
  bf16_t* Qbuf  = (bf16_t*)alloc((size_t)32 * 1024 * 64 * 2);
  bf16_t* Kbuf  = (bf16_t*)alloc((size_t)32 * 1024 * 64 * 2);
  bf16_t* Vt    = (bf16_t*)alloc((size_t)32 * 64 * 1024 * 2);
  bf16_t* Ob    = (bf16_t*)alloc((size_t)2048 * 1024 * 2);
  float*  t0    = (float*) alloc((size_t)2048 * 1024 * 4);
  float*  x1    = (float*) alloc((size_t)2048 * 1024 * 4);
  bf16_t* x1b   = (bf16_t*)alloc((size_t)2048 * 1024 * 2);
  bf16_t* hb    = (bf16_t*)qkv;  // alias: qkv dead once hb is produced
  if (off > ws_size) return;     // workspace too small -> loud validation fail

  ln_kernel<<<2048, 256, 0, stream>>>(src, nullptr, ln0g, ln0b, 32.0f, x, xb);

  for (int l = 0; l < 4; l++) {
    const float* wq = Wq + (size_t)l * 1024 * 1024;
    const float* wk = Wk + (size_t)l * 1024 * 1024;
    const float* wv = Wv + (size_t)l * 1024 * 1024;
    const float* wo = Wo + (size_t)l * 1024 * 1024;
    const float* w1 = W1 + (size_t)l * 1024 * 4096;
    const float* w2 = W2 + (size_t)l * 4096 * 1024;

    conv_t_kernel<<<dim3(16, 16), 256, 0, stream>>>(wq, wqkvt, 1024, 1024);
    conv_t_kernel<<<dim3(16, 16), 256, 0, stream>>>(wk, wqkvt + (size_t)1024 * 1024, 1024, 1024);
    conv_t_kernel<<<dim3(16, 16), 256, 0, stream>>>(wv, wqkvt + (size_t)2048 * 1024, 1024, 1024);
    conv_t_kernel<<<dim3(16, 16), 256, 0, stream>>>(wo, wot, 1024, 1024);
    conv_t_kernel<<<dim3(16, 64), 256, 0, stream>>>(w1, w1t, 1024, 4096);
    conv_t_kernel<<<dim3(64, 16), 256, 0, stream>>>(w2, w2t, 4096, 1024);

    gemm_kernel<0><<<dim3(16, 48), 256, 0, stream>>>(xb, wqkvt, nullptr, qkv, nullptr, 3072, 1024);
    rope_kernel<<<2048, 256, 0, stream>>>(qkv, Qbuf, Kbuf);
    vtrans_kernel<<<dim3(32, 16), 256, 0, stream>>>(qkv, Vt);
    attn_kernel<<<dim3(32, 16), 256, 0, stream>>>(Qbuf, Kbuf, Vt, Ob);
    gemm_kernel<0><<<dim3(16, 16), 256, 0, stream>>>(Ob, wot, nullptr, t0, nullptr, 1024, 1024);
    ln_kernel<<<2048, 256, 0, stream>>>(t0, x, ln1g + (size_t)l * 1024,
                                        ln1b + (size_t)l * 1024, 1.0f, x1, x1b);
    gemm_kernel<1><<<dim3(16, 64), 256, 0, stream>>>(x1b, w1t, b1 + (size_t)l * 4096,
                                                     nullptr, hb, 4096, 1024);
    gemm_kernel<2><<<dim3(16, 16), 256, 0, stream>>>(hb, w2t, b2 + (size_t)l * 1024,
                                                     t0, nullptr, 1024, 4096);
    const bool last = (l == 3);
    ln_kernel<<<2048, 256, 0, stream>>>(t0, x1, ln2g + (size_t)l * 1024,
                                        ln2b + (size_t)l * 1024, 1.0f,
                                        last ? (float*)d_out : x,
                                        last ? nullptr : xb);
  }
}

// Round 3
// 789.829 us; speedup vs baseline: 1.1280x; 1.1280x over previous
//
#include <hip/hip_runtime.h>
#include <hip/hip_bf16.h>
#include <cstdint>
#include <cstddef>

typedef __bf16 bf16_t;
typedef __bf16 bf16x8 __attribute__((ext_vector_type(8)));
typedef __bf16 bf16x4 __attribute__((ext_vector_type(4)));
typedef float  f32x4  __attribute__((ext_vector_type(4)));

#define DEV __device__ __forceinline__

DEV void gload16(void* lds, const void* gmem) {
  __builtin_amdgcn_global_load_lds(
      (const __attribute__((address_space(1))) void*)gmem,
      (__attribute__((address_space(3))) void*)lds, 16, 0, 0);
}

DEV f32x4 mfma16(bf16x8 a, bf16x8 b, f32x4 c) {
  return __builtin_amdgcn_mfma_f32_16x16x32_bf16(a, b, c, 0, 0, 0);
}

// ---------------------------------------------------------------------------
// Weight convert + transpose: src fp32 [K][N] -> dst bf16 [N][K]
// ---------------------------------------------------------------------------
__global__ __launch_bounds__(256)
void conv_t_kernel(const float* __restrict__ src, bf16_t* __restrict__ dst,
                   int K, int N) {
  __shared__ float tile[64][65];
  const int k0 = blockIdx.x * 64, n0 = blockIdx.y * 64;
  const int t = threadIdx.x;
#pragma unroll
  for (int c = 0; c < 16; c++) {
    int idx = c * 256 + t;
    int r = idx >> 6, cc = idx & 63;
    tile[r][cc] = src[(size_t)(k0 + r) * N + n0 + cc];
  }
  __syncthreads();
#pragma unroll
  for (int c = 0; c < 16; c++) {
    int idx = c * 256 + t;
    int r = idx >> 6, cc = idx & 63;
    dst[(size_t)(n0 + r) * K + k0 + cc] = (bf16_t)tile[cc][r];
  }
}

// Batched 4x (1024x1024) convert+transpose, z selects tensor.
__global__ __launch_bounds__(256)
void conv4_kernel(const float* __restrict__ w0, const float* __restrict__ w1,
                  const float* __restrict__ w2, const float* __restrict__ w3,
                  bf16_t* __restrict__ d0, bf16_t* __restrict__ d1,
                  bf16_t* __restrict__ d2, bf16_t* __restrict__ d3) {
  const float* src = (blockIdx.z == 0) ? w0 : (blockIdx.z == 1) ? w1
                     : (blockIdx.z == 2) ? w2 : w3;
  bf16_t* dst = (blockIdx.z == 0) ? d0 : (blockIdx.z == 1) ? d1
                : (blockIdx.z == 2) ? d2 : d3;
  __shared__ float tile[64][65];
  const int k0 = blockIdx.x * 64, n0 = blockIdx.y * 64;
  const int t = threadIdx.x;
#pragma unroll
  for (int c = 0; c < 16; c++) {
    int idx = c * 256 + t;
    int r = idx >> 6, cc = idx & 63;
    tile[r][cc] = src[(size_t)(k0 + r) * 1024 + n0 + cc];
  }
  __syncthreads();
#pragma unroll
  for (int c = 0; c < 16; c++) {
    int idx = c * 256 + t;
    int r = idx >> 6, cc = idx & 63;
    dst[(size_t)(n0 + r) * 1024 + k0 + cc] = (bf16_t)tile[cc][r];
  }
}

// ---------------------------------------------------------------------------
// LayerNorm over D=1024: out = (in*alpha + resid - mu)*rsqrt(var+eps)*g + b
// ---------------------------------------------------------------------------
__global__ __launch_bounds__(256)
void ln_kernel(const float* __restrict__ in, const float* __restrict__ resid,
               const float* __restrict__ g, const float* __restrict__ bt,
               float alpha, float* __restrict__ outf, bf16_t* __restrict__ outb) {
  const int row = blockIdx.x, t = threadIdx.x;
  const float4 vi = *(const float4*)(in + (size_t)row * 1024 + t * 4);
  float x0 = vi.x * alpha, x1 = vi.y * alpha, x2 = vi.z * alpha, x3 = vi.w * alpha;
  if (resid) {
    const float4 rv = *(const float4*)(resid + (size_t)row * 1024 + t * 4);
    x0 += rv.x; x1 += rv.y; x2 += rv.z; x3 += rv.w;
  }
  float s = x0 + x1 + x2 + x3;
  float sq = x0 * x0 + x1 * x1 + x2 * x2 + x3 * x3;
#pragma unroll
  for (int m = 1; m < 64; m <<= 1) { s += __shfl_xor(s, m); sq += __shfl_xor(sq, m); }
  __shared__ float ps[4], pq[4];
  const int wave = t >> 6;
  if ((t & 63) == 0) { ps[wave] = s; pq[wave] = sq; }
  __syncthreads();
  s = ps[0] + ps[1] + ps[2] + ps[3];
  sq = pq[0] + pq[1] + pq[2] + pq[3];
  const float mu = s * (1.0f / 1024.0f);
  const float var = sq * (1.0f / 1024.0f) - mu * mu;
  const float rs = rsqrtf(var + 1e-6f);
  const float4 gv = *(const float4*)(g + t * 4);
  const float4 bv = *(const float4*)(bt + t * 4);
  float y0 = (x0 - mu) * rs * gv.x + bv.x;
  float y1 = (x1 - mu) * rs * gv.y + bv.y;
  float y2 = (x2 - mu) * rs * gv.z + bv.z;
  float y3 = (x3 - mu) * rs * gv.w + bv.w;
  if (outf) *(float4*)(outf + (size_t)row * 1024 + t * 4) = make_float4(y0, y1, y2, y3);
  if (outb) {
    bf16x4 o; o[0] = (bf16_t)y0; o[1] = (bf16_t)y1; o[2] = (bf16_t)y2; o[3] = (bf16_t)y3;
    *(bf16x4*)(outb + (size_t)row * 1024 + t * 4) = o;
  }
}

// ---------------------------------------------------------------------------
// GEMM: C[2048][N] = A[2048][K] @ Bt[N][K]^T, bf16 in, fp32 accum.
// BM=BN=128, BK=64, 4 waves (2x2, each 64x64), double-buffered LDS,
// global_load_lds width-16 staging with XOR(row&7) 16B-slot swizzle.
// EPI: 0 = f32 out; 1 = +bias, relu, bf16 out; 3 = f32 partial (split-K, z).
// ---------------------------------------------------------------------------
template <int EPI>
__global__ __launch_bounds__(256, 2)
void gemm128(const bf16_t* __restrict__ A, const bf16_t* __restrict__ Bt,
             const float* __restrict__ bias, float* __restrict__ Cf,
             bf16_t* __restrict__ Cb, int N, int K, int KL) {
  constexpr int BM = 128, BN = 128, BK = 64;
  __shared__ __align__(16) bf16_t As[2][BM * BK];
  __shared__ __align__(16) bf16_t Bs[2][BN * BK];
  const int tid = threadIdx.x;
  const int wave = tid >> 6, lane = tid & 63;
  const int l16 = lane & 15, l4 = lane >> 4;
  const int m0 = blockIdx.x * BM, n0 = blockIdx.y * BN;
  const int wm = wave >> 1, wn = wave & 1;
  const int kbase = blockIdx.z * KL;
  f32x4 acc[4][4] = {};

  const int nt = KL / BK;
  auto stage = [&](int buf, int k0) {
#pragma unroll
    for (int c = 0; c < 4; c++) {
      int gidx = c * 256 + tid;
      int row = gidx >> 3, s = gidx & 7;
      gload16(&As[buf][(c * 256 + wave * 64) * 8],
              A + (size_t)(m0 + row) * K + kbase + k0 + ((s ^ (row & 7)) << 3));
    }
#pragma unroll
    for (int c = 0; c < 4; c++) {
      int gidx = c * 256 + tid;
      int row = gidx >> 3, s = gidx & 7;
      gload16(&Bs[buf][(c * 256 + wave * 64) * 8],
              Bt + (size_t)(n0 + row) * K + kbase + k0 + ((s ^ (row & 7)) << 3));
    }
  };

  stage(0, 0);
  __syncthreads();
  for (int t = 0; t < nt; t++) {
    const int cur = t & 1;
    if (t + 1 < nt) stage(cur ^ 1, (t + 1) * BK);
    const bf16_t* as = As[cur];
    const bf16_t* bs = Bs[cur];
#pragma unroll
    for (int kk = 0; kk < 2; kk++) {
      bf16x8 af[4], bfr[4];
#pragma unroll
      for (int m = 0; m < 4; m++) {
        int row = wm * 64 + m * 16 + l16;
        af[m] = *(const bf16x8*)(as + row * 64 + ((((kk << 2) + l4) ^ (row & 7)) << 3));
      }
#pragma unroll
      for (int n = 0; n < 4; n++) {
        int row = wn * 64 + n * 16 + l16;
        bfr[n] = *(const bf16x8*)(bs + row * 64 + ((((kk << 2) + l4) ^ (row & 7)) << 3));
      }
#pragma unroll
      for (int m = 0; m < 4; m++)
#pragma unroll
        for (int n = 0; n < 4; n++)
          acc[m][n] = mfma16(af[m], bfr[n], acc[m][n]);
    }
    __syncthreads();
  }

#pragma unroll
  for (int m = 0; m < 4; m++) {
#pragma unroll
    for (int n = 0; n < 4; n++) {
      int col = n0 + wn * 64 + n * 16 + l16;
      float bv = (EPI == 1) ? bias[col] : 0.0f;
#pragma unroll
      for (int r = 0; r < 4; r++) {
        int row = m0 + wm * 64 + m * 16 + l4 * 4 + r;
        float v = acc[m][n][r] + bv;
        if (EPI == 1) {
          v = fmaxf(v, 0.0f);
          Cb[(size_t)row * N + col] = (bf16_t)v;
        } else if (EPI == 3) {
          Cf[(size_t)blockIdx.z * 2048 * N + (size_t)row * N + col] = v;
        } else {
          Cf[(size_t)row * N + col] = v;
        }
      }
    }
  }
}

// Sum S split-K partials (+optional bias) -> f32 out. N==1024.
__global__ __launch_bounds__(256)
void reduce_kernel(const float* __restrict__ parts, const float* __restrict__ bias,
                   float* __restrict__ out, int S) {
  const int row = blockIdx.x, c4 = threadIdx.x * 4;
  f32x4 a = *(const f32x4*)(parts + (size_t)row * 1024 + c4);
  for (int s = 1; s < S; s++)
    a += *(const f32x4*)(parts + (size_t)s * 2048 * 1024 + (size_t)row * 1024 + c4);
  if (bias) a += *(const f32x4*)(bias + c4);
  *(f32x4*)(out + (size_t)row * 1024 + c4) = a;
}

// ---------------------------------------------------------------------------
// RoPE (head-indexed tables, pos = 1008+h) + 1/sqrt(DK) fold into Q.
// ---------------------------------------------------------------------------
__global__ __launch_bounds__(256)
void rope_kernel(const float* __restrict__ qkv, bf16_t* __restrict__ Qb,
                 bf16_t* __restrict__ Kb) {
  const int m = blockIdx.x, t = threadIdx.x;
  const int h = t >> 4, i = t & 15;
  const int b = m >> 10, l = m & 1023;
  const float pos = (float)(1008 + h);
  const float ang = pos * exp2f(-0.75f * (float)i);
  float sn, cs;
  sincosf(ang, &sn, &cs);
  const float* q = qkv + (size_t)m * 3072 + h * 64;
  const float* k = q + 1024;
  const size_t ob = ((size_t)(b * 16 + h) * 1024 + l) * 64;
  const float it = 0.125f;
  float qi = q[i], qj = q[i + 16];
  Qb[ob + i]      = (bf16_t)((qi * cs - qj * sn) * it);
  Qb[ob + i + 16] = (bf16_t)((qj * cs + qi * sn) * it);
  Qb[ob + i + 32] = (bf16_t)(q[i + 32] * it);
  Qb[ob + i + 48] = (bf16_t)(q[i + 48] * it);
  float ki = k[i], kj = k[i + 16];
  Kb[ob + i]      = (bf16_t)(ki * cs - kj * sn);
  Kb[ob + i + 16] = (bf16_t)(kj * cs + ki * sn);
  Kb[ob + i + 32] = (bf16_t)k[i + 32];
  Kb[ob + i + 48] = (bf16_t)k[i + 48];
}

// ---------------------------------------------------------------------------
// V transpose: qkv fp32 [2048][3072] -> Vt bf16 [32][64][1024]
// ---------------------------------------------------------------------------
__global__ __launch_bounds__(256)
void vtrans_kernel(const float* __restrict__ qkv, bf16_t* __restrict__ Vt) {
  const int bh = blockIdx.x, lt = blockIdx.y;
  const int b = bh >> 4, h = bh & 15;
  __shared__ float tile[64][65];
  const int t = threadIdx.x;
#pragma unroll
  for (int c = 0; c < 16; c++) {
    int idx = c * 256 + t;
    int r = idx >> 6, d = idx & 63;
    tile[r][d] = qkv[(size_t)(b * 1024 + lt * 64 + r) * 3072 + 2048 + h * 64 + d];
  }
  __syncthreads();
#pragma unroll
  for (int c = 0; c < 16; c++) {
    int idx = c * 256 + t;
    int d = idx >> 6, r = idx & 63;
    Vt[((size_t)bh * 64 + d) * 1024 + lt * 64 + r] = (bf16_t)tile[r][d];
  }
}

// ---------------------------------------------------------------------------
// Attention: block = (bh, 64 q-rows), 8 waves. Waves 0-3: keys [0,512),
// waves 4-7: keys [512,1024), same 16-q-row split. Merge partials via LDS.
// NOTE: lrow held per-lane is a PARTIAL row-sum (this lane's l16 column
// slice); it MUST be shfl-reduced across the 16-lane group before the merge.
// ---------------------------------------------------------------------------
__global__ __launch_bounds__(512, 2)
void attn_kernel(const bf16_t* __restrict__ Qb, const bf16_t* __restrict__ Kb,
                 const bf16_t* __restrict__ Vt, bf16_t* __restrict__ Ob) {
  const int bh = blockIdx.x;
  const int q0 = blockIdx.y * 64;
  const int wave = threadIdx.x >> 6, lane = threadIdx.x & 63;
  const int l16 = lane & 15, l4 = lane >> 4;
  const int qw = wave & 3, kh = wave >> 2;
  const bf16_t* Q = Qb + (size_t)bh * 65536;
  const bf16_t* K = Kb + (size_t)bh * 65536;
  const bf16_t* V = Vt + (size_t)bh * 65536;
  __shared__ __align__(16) bf16_t Plds[8][16 * 64];
  __shared__ float Olds[4][16][68];
  __shared__ float mlds[4][16], llds[4][16];
  bf16_t* pl = Plds[wave];

  const int qrow = q0 + qw * 16 + l16;
  const bf16x8 qf0 = *(const bf16x8*)(Q + (size_t)qrow * 64 + l4 * 8);
  const bf16x8 qf1 = *(const bf16x8*)(Q + (size_t)qrow * 64 + 32 + l4 * 8);

  f32x4 o[4] = {};
  float mrow[4] = {-1e30f, -1e30f, -1e30f, -1e30f};
  float lrow[4] = {0.f, 0.f, 0.f, 0.f};
  constexpr float L2E = 1.44269504088896340736f;

  for (int kt = 0; kt < 8; kt++) {
    const int j0 = (kh << 9) + kt * 64;
    f32x4 s[4] = {};
#pragma unroll
    for (int nf = 0; nf < 4; nf++) {
      const bf16_t* kp = K + (size_t)(j0 + nf * 16 + l16) * 64;
      bf16x8 k0 = *(const bf16x8*)(kp + l4 * 8);
      bf16x8 k1 = *(const bf16x8*)(kp + 32 + l4 * 8);
      s[nf] = mfma16(qf0, k0, s[nf]);
      s[nf] = mfma16(qf1, k1, s[nf]);
    }
#pragma unroll
    for (int r = 0; r < 4; r++) {
      float tm = fmaxf(fmaxf(s[0][r], s[1][r]), fmaxf(s[2][r], s[3][r]));
      tm = fmaxf(tm, __shfl_xor(tm, 1));
      tm = fmaxf(tm, __shfl_xor(tm, 2));
      tm = fmaxf(tm, __shfl_xor(tm, 4));
      tm = fmaxf(tm, __shfl_xor(tm, 8));
      const float mnew = fmaxf(mrow[r], tm);
      const float c = exp2f((mrow[r] - mnew) * L2E);
      mrow[r] = mnew;
      lrow[r] *= c;
      o[0][r] *= c; o[1][r] *= c; o[2][r] *= c; o[3][r] *= c;
      const int prow = l4 * 4 + r;
      const int rs = prow & 7;
#pragma unroll
      for (int nf = 0; nf < 4; nf++) {
        float p = exp2f((s[nf][r] - mnew) * L2E);
        lrow[r] += p;
        int gran = (nf << 1) + (l16 >> 3);
        pl[(prow << 6) + ((gran ^ rs) << 3) + (l16 & 7)] = (bf16_t)p;
      }
    }
#pragma unroll
    for (int jc = 0; jc < 2; jc++) {
      const int prow = l16;
      bf16x8 pf = *(const bf16x8*)(pl + (prow << 6) +
                                   ((((jc << 2) + l4) ^ (prow & 7)) << 3));
#pragma unroll
      for (int df = 0; df < 4; df++) {
        bf16x8 vf = *(const bf16x8*)(V + (size_t)(df * 16 + l16) * 1024 + j0 +
                                     jc * 32 + l4 * 8);
        o[df] = mfma16(pf, vf, o[df]);
      }
    }
  }

  // Cross-lane reduce lrow partials -> full per-row sums (uniform in l16).
#pragma unroll
  for (int r = 0; r < 4; r++) {
    float lr = lrow[r];
    lr += __shfl_xor(lr, 1);
    lr += __shfl_xor(lr, 2);
    lr += __shfl_xor(lr, 4);
    lr += __shfl_xor(lr, 8);
    lrow[r] = lr;
  }

  if (kh == 1) {
#pragma unroll
    for (int r = 0; r < 4; r++) {
      if (l16 == 0) {
        mlds[qw][l4 * 4 + r] = mrow[r];
        llds[qw][l4 * 4 + r] = lrow[r];
      }
#pragma unroll
      for (int df = 0; df < 4; df++)
        Olds[qw][l4 * 4 + r][df * 16 + l16] = o[df][r];
    }
  }
  __syncthreads();
  if (kh == 0) {
    const int b = bh >> 4, h = bh & 15;
    float sa[4], sb[4];
#pragma unroll
    for (int r = 0; r < 4; r++) {
      const int rowl = l4 * 4 + r;
      const float pm = mlds[qw][rowl], pll = llds[qw][rowl];
      const float mn = fmaxf(mrow[r], pm);
      const float a = exp2f((mrow[r] - mn) * L2E);
      const float bsc = exp2f((pm - mn) * L2E);
      const float inv = 1.0f / (lrow[r] * a + pll * bsc);
      sa[r] = a * inv; sb[r] = bsc * inv;
    }
#pragma unroll
    for (int df = 0; df < 4; df++) {
#pragma unroll
      for (int r = 0; r < 4; r++) {
        const int rowl = l4 * 4 + r;
        const int rl = q0 + qw * 16 + rowl;
        const float v = o[df][r] * sa[r] + Olds[qw][rowl][df * 16 + l16] * sb[r];
        Ob[((size_t)(b * 1024 + rl)) * 1024 + h * 64 + df * 16 + l16] = (bf16_t)v;
      }
    }
  }
}

// ---------------------------------------------------------------------------
extern "C" void kernel_launch(void* const* d_in, const int* in_sizes, int n_in,
                              void* d_out, int out_size, void* d_ws, size_t ws_size,
                              hipStream_t stream) {
  (void)in_sizes; (void)n_in; (void)out_size;
  const float* src  = (const float*)d_in[0];
  const float* Wq   = (const float*)d_in[1];
  const float* Wk   = (const float*)d_in[2];
  const float* Wv   = (const float*)d_in[3];
  const float* Wo   = (const float*)d_in[4];
  const float* ln1g = (const float*)d_in[5];
  const float* ln1b = (const float*)d_in[6];
  const float* W1   = (const float*)d_in[7];
  const float* b1   = (const float*)d_in[8];
  const float* W2   = (const float*)d_in[9];
  const float* b2   = (const float*)d_in[10];
  const float* ln2g = (const float*)d_in[11];
  const float* ln2b = (const float*)d_in[12];
  const float* ln0g = (const float*)d_in[13];
  const float* ln0b = (const float*)d_in[14];

  char* ws = (char*)d_ws;
  size_t off = 0;
  auto alloc = [&](size_t bytes) -> char* {
    char* p = ws + off;
    off += (bytes + 255) & ~(size_t)255;
    return p;
  };
  bf16_t* wqkvt = (bf16_t*)alloc((size_t)3072 * 1024 * 2);
  bf16_t* wot   = (bf16_t*)alloc((size_t)1024 * 1024 * 2);
  bf16_t* w1t   = (bf16_t*)alloc((size_t)4096 * 1024 * 2);
  bf16_t* w2t   = (bf16_t*)alloc((size_t)1024 * 4096 * 2);
  float*  x     = (float*) alloc((size_t)2048 * 1024 * 4);
  bf16_t* xb    = (bf16_t*)alloc((size_t)2048 * 1024 * 2);
  float*  x1    = (float*) alloc((size_t)2048 * 1024 * 4);
  bf16_t* x1b   = (bf16_t*)alloc((size_t)2048 * 1024 * 2);
  float*  t0    = (float*) alloc((size_t)2048 * 1024 * 4);
  char*   R     = alloc((size_t)48 * 1024 * 1024);
  // Phase-1 views of R (QKV -> attention):
  float*  qkv   = (float*)R;                                      // 24 MB
  bf16_t* Qbuf  = (bf16_t*)(R + (size_t)24 * 1024 * 1024);        //  4 MB
  bf16_t* Kbuf  = (bf16_t*)(R + (size_t)28 * 1024 * 1024);        //  4 MB
  bf16_t* Vt    = (bf16_t*)(R + (size_t)32 * 1024 * 1024);        //  4 MB
  bf16_t* Ob    = (bf16_t*)(R + (size_t)36 * 1024 * 1024);        //  4 MB
  // Phase-2 views of R (post-attention):
  float*  parts = (float*)R;                                      // up to 32 MB
  bf16_t* hb    = (bf16_t*)(R + (size_t)32 * 1024 * 1024);        // 16 MB
  if (off > ws_size) return;

  ln_kernel<<<2048, 256, 0, stream>>>(src, nullptr, ln0g, ln0b, 32.0f, x, xb);

  for (int l = 0; l < 4; l++) {
    const float* wq = Wq + (size_t)l * 1024 * 1024;
    const float* wk = Wk + (size_t)l * 1024 * 1024;
    const float* wv = Wv + (size_t)l * 1024 * 1024;
    const float* wo = Wo + (size_t)l * 1024 * 1024;
    const float* w1 = W1 + (size_t)l * 1024 * 4096;
    const float* w2 = W2 + (size_t)l * 4096 * 1024;

    conv4_kernel<<<dim3(16, 16, 4), 256, 0, stream>>>(
        wq, wk, wv, wo, wqkvt, wqkvt + (size_t)1024 * 1024,
        wqkvt + (size_t)2048 * 1024, wot);
    conv_t_kernel<<<dim3(16, 64), 256, 0, stream>>>(w1, w1t, 1024, 4096);
    conv_t_kernel<<<dim3(64, 16), 256, 0, stream>>>(w2, w2t, 4096, 1024);

    gemm128<0><<<dim3(16, 24, 1), 256, 0, stream>>>(xb, wqkvt, nullptr, qkv, nullptr,
                                                    3072, 1024, 1024);
    rope_kernel<<<2048, 256, 0, stream>>>(qkv, Qbuf, Kbuf);
    vtrans_kernel<<<dim3(32, 16), 256, 0, stream>>>(qkv, Vt);
    attn_kernel<<<dim3(32, 16), 512, 0, stream>>>(Qbuf, Kbuf, Vt, Ob);

    gemm128<3><<<dim3(16, 8, 2), 256, 0, stream>>>(Ob, wot, nullptr, parts, nullptr,
                                                   1024, 1024, 512);
    reduce_kernel<<<2048, 256, 0, stream>>>(parts, nullptr, t0, 2);
    ln_kernel<<<2048, 256, 0, stream>>>(t0, x, ln1g + (size_t)l * 1024,
                                        ln1b + (size_t)l * 1024, 1.0f, x1, x1b);

    gemm128<1><<<dim3(16, 32, 1), 256, 0, stream>>>(x1b, w1t, b1 + (size_t)l * 4096,
                                                    nullptr, hb, 4096, 1024, 1024);
    gemm128<3><<<dim3(16, 8, 4), 256, 0, stream>>>(hb, w2t, nullptr, parts, nullptr,
                                                   1024, 4096, 1024);
    reduce_kernel<<<2048, 256, 0, stream>>>(parts, b2 + (size_t)l * 1024, t0, 4);

    const bool last = (l == 3);
    ln_kernel<<<2048, 256, 0, stream>>>(t0, x1, ln2g + (size_t)l * 1024,
                                        ln2b + (size_t)l * 1024, 1.0f,
                                        last ? (float*)d_out : x,
                                        last ? nullptr : xb);
  }
}

// Round 4
// 689.679 us; speedup vs baseline: 1.2918x; 1.1452x over previous
//
#include <hip/hip_runtime.h>
#include <hip/hip_bf16.h>
#include <cstdint>
#include <cstddef>

typedef __bf16 bf16_t;
typedef __bf16 bf16x8 __attribute__((ext_vector_type(8)));
typedef __bf16 bf16x4 __attribute__((ext_vector_type(4)));
typedef float  f32x4  __attribute__((ext_vector_type(4)));
typedef float  f32x16 __attribute__((ext_vector_type(16)));

#define DEV __device__ __forceinline__

DEV void gload16(void* lds, const void* gmem) {
  __builtin_amdgcn_global_load_lds(
      (const __attribute__((address_space(1))) void*)gmem,
      (__attribute__((address_space(3))) void*)lds, 16, 0, 0);
}

DEV f32x4 mfma16(bf16x8 a, bf16x8 b, f32x4 c) {
  return __builtin_amdgcn_mfma_f32_16x16x32_bf16(a, b, c, 0, 0, 0);
}
DEV f32x16 mfma32(bf16x8 a, bf16x8 b, f32x16 c) {
  return __builtin_amdgcn_mfma_f32_32x32x16_bf16(a, b, c, 0, 0, 0);
}

DEV uint32_t pkbf(float a, float b) {
  union { bf16_t h; uint16_t u; } ua, ub;
  ua.h = (bf16_t)a; ub.h = (bf16_t)b;
  return (uint32_t)ua.u | ((uint32_t)ub.u << 16);
}

// ---------------------------------------------------------------------------
// Weight convert + transpose: src fp32 [K][N] -> dst bf16 [N][K]
// ---------------------------------------------------------------------------
__global__ __launch_bounds__(256)
void conv_t_kernel(const float* __restrict__ src, bf16_t* __restrict__ dst,
                   int K, int N) {
  __shared__ float tile[64][65];
  const int k0 = blockIdx.x * 64, n0 = blockIdx.y * 64;
  const int t = threadIdx.x;
#pragma unroll
  for (int c = 0; c < 16; c++) {
    int idx = c * 256 + t;
    int r = idx >> 6, cc = idx & 63;
    tile[r][cc] = src[(size_t)(k0 + r) * N + n0 + cc];
  }
  __syncthreads();
#pragma unroll
  for (int c = 0; c < 16; c++) {
    int idx = c * 256 + t;
    int r = idx >> 6, cc = idx & 63;
    dst[(size_t)(n0 + r) * K + k0 + cc] = (bf16_t)tile[cc][r];
  }
}

// Batched 4x (1024x1024) convert+transpose, z selects tensor.
__global__ __launch_bounds__(256)
void conv4_kernel(const float* __restrict__ w0, const float* __restrict__ w1,
                  const float* __restrict__ w2, const float* __restrict__ w3,
                  bf16_t* __restrict__ d0, bf16_t* __restrict__ d1,
                  bf16_t* __restrict__ d2, bf16_t* __restrict__ d3) {
  const float* src = (blockIdx.z == 0) ? w0 : (blockIdx.z == 1) ? w1
                     : (blockIdx.z == 2) ? w2 : w3;
  bf16_t* dst = (blockIdx.z == 0) ? d0 : (blockIdx.z == 1) ? d1
                : (blockIdx.z == 2) ? d2 : d3;
  __shared__ float tile[64][65];
  const int k0 = blockIdx.x * 64, n0 = blockIdx.y * 64;
  const int t = threadIdx.x;
#pragma unroll
  for (int c = 0; c < 16; c++) {
    int idx = c * 256 + t;
    int r = idx >> 6, cc = idx & 63;
    tile[r][cc] = src[(size_t)(k0 + r) * 1024 + n0 + cc];
  }
  __syncthreads();
#pragma unroll
  for (int c = 0; c < 16; c++) {
    int idx = c * 256 + t;
    int r = idx >> 6, cc = idx & 63;
    dst[(size_t)(n0 + r) * 1024 + k0 + cc] = (bf16_t)tile[cc][r];
  }
}

// ---------------------------------------------------------------------------
// LayerNorm over D=1024: out = (in*alpha + resid - mu)*rsqrt(var+eps)*g + b
// ---------------------------------------------------------------------------
__global__ __launch_bounds__(256)
void ln_kernel(const float* __restrict__ in, const float* __restrict__ resid,
               const float* __restrict__ g, const float* __restrict__ bt,
               float alpha, float* __restrict__ outf, bf16_t* __restrict__ outb) {
  const int row = blockIdx.x, t = threadIdx.x;
  const float4 vi = *(const float4*)(in + (size_t)row * 1024 + t * 4);
  float x0 = vi.x * alpha, x1 = vi.y * alpha, x2 = vi.z * alpha, x3 = vi.w * alpha;
  if (resid) {
    const float4 rv = *(const float4*)(resid + (size_t)row * 1024 + t * 4);
    x0 += rv.x; x1 += rv.y; x2 += rv.z; x3 += rv.w;
  }
  float s = x0 + x1 + x2 + x3;
  float sq = x0 * x0 + x1 * x1 + x2 * x2 + x3 * x3;
#pragma unroll
  for (int m = 1; m < 64; m <<= 1) { s += __shfl_xor(s, m); sq += __shfl_xor(sq, m); }
  __shared__ float ps[4], pq[4];
  const int wave = t >> 6;
  if ((t & 63) == 0) { ps[wave] = s; pq[wave] = sq; }
  __syncthreads();
  s = ps[0] + ps[1] + ps[2] + ps[3];
  sq = pq[0] + pq[1] + pq[2] + pq[3];
  const float mu = s * (1.0f / 1024.0f);
  const float var = sq * (1.0f / 1024.0f) - mu * mu;
  const float rs = rsqrtf(var + 1e-6f);
  const float4 gv = *(const float4*)(g + t * 4);
  const float4 bv = *(const float4*)(bt + t * 4);
  float y0 = (x0 - mu) * rs * gv.x + bv.x;
  float y1 = (x1 - mu) * rs * gv.y + bv.y;
  float y2 = (x2 - mu) * rs * gv.z + bv.z;
  float y3 = (x3 - mu) * rs * gv.w + bv.w;
  if (outf) *(float4*)(outf + (size_t)row * 1024 + t * 4) = make_float4(y0, y1, y2, y3);
  if (outb) {
    bf16x4 o; o[0] = (bf16_t)y0; o[1] = (bf16_t)y1; o[2] = (bf16_t)y2; o[3] = (bf16_t)y3;
    *(bf16x4*)(outb + (size_t)row * 1024 + t * 4) = o;
  }
}

// ---------------------------------------------------------------------------
// GEMM: C[2048][N] = A[2048][K] @ Bt[N][K]^T, bf16 in, fp32 accum.
// BM=BN=128, BK=64, 4 waves (2x2, each 64x64), double-buffered LDS,
// global_load_lds width-16 staging with XOR(row&7) 16B-slot swizzle.
// EPI: 0 = f32 out; 1 = +bias, relu, bf16 out; 3 = f32 partial (split-K, z).
// ---------------------------------------------------------------------------
template <int EPI>
__global__ __launch_bounds__(256, 2)
void gemm128(const bf16_t* __restrict__ A, const bf16_t* __restrict__ Bt,
             const float* __restrict__ bias, float* __restrict__ Cf,
             bf16_t* __restrict__ Cb, int N, int K, int KL) {
  constexpr int BM = 128, BN = 128, BK = 64;
  __shared__ __align__(16) bf16_t As[2][BM * BK];
  __shared__ __align__(16) bf16_t Bs[2][BN * BK];
  const int tid = threadIdx.x;
  const int wave = tid >> 6, lane = tid & 63;
  const int l16 = lane & 15, l4 = lane >> 4;
  const int m0 = blockIdx.x * BM, n0 = blockIdx.y * BN;
  const int wm = wave >> 1, wn = wave & 1;
  const int kbase = blockIdx.z * KL;
  f32x4 acc[4][4] = {};

  const int nt = KL / BK;
  auto stage = [&](int buf, int k0) {
#pragma unroll
    for (int c = 0; c < 4; c++) {
      int gidx = c * 256 + tid;
      int row = gidx >> 3, s = gidx & 7;
      gload16(&As[buf][(c * 256 + wave * 64) * 8],
              A + (size_t)(m0 + row) * K + kbase + k0 + ((s ^ (row & 7)) << 3));
    }
#pragma unroll
    for (int c = 0; c < 4; c++) {
      int gidx = c * 256 + tid;
      int row = gidx >> 3, s = gidx & 7;
      gload16(&Bs[buf][(c * 256 + wave * 64) * 8],
              Bt + (size_t)(n0 + row) * K + kbase + k0 + ((s ^ (row & 7)) << 3));
    }
  };

  stage(0, 0);
  __syncthreads();
  for (int t = 0; t < nt; t++) {
    const int cur = t & 1;
    if (t + 1 < nt) stage(cur ^ 1, (t + 1) * BK);
    const bf16_t* as = As[cur];
    const bf16_t* bs = Bs[cur];
#pragma unroll
    for (int kk = 0; kk < 2; kk++) {
      bf16x8 af[4], bfr[4];
#pragma unroll
      for (int m = 0; m < 4; m++) {
        int row = wm * 64 + m * 16 + l16;
        af[m] = *(const bf16x8*)(as + row * 64 + ((((kk << 2) + l4) ^ (row & 7)) << 3));
      }
#pragma unroll
      for (int n = 0; n < 4; n++) {
        int row = wn * 64 + n * 16 + l16;
        bfr[n] = *(const bf16x8*)(bs + row * 64 + ((((kk << 2) + l4) ^ (row & 7)) << 3));
      }
#pragma unroll
      for (int m = 0; m < 4; m++)
#pragma unroll
        for (int n = 0; n < 4; n++)
          acc[m][n] = mfma16(af[m], bfr[n], acc[m][n]);
    }
    __syncthreads();
  }

#pragma unroll
  for (int m = 0; m < 4; m++) {
#pragma unroll
    for (int n = 0; n < 4; n++) {
      int col = n0 + wn * 64 + n * 16 + l16;
      float bv = (EPI == 1) ? bias[col] : 0.0f;
#pragma unroll
      for (int r = 0; r < 4; r++) {
        int row = m0 + wm * 64 + m * 16 + l4 * 4 + r;
        float v = acc[m][n][r] + bv;
        if (EPI == 1) {
          v = fmaxf(v, 0.0f);
          Cb[(size_t)row * N + col] = (bf16_t)v;
        } else if (EPI == 3) {
          Cf[(size_t)blockIdx.z * 2048 * N + (size_t)row * N + col] = v;
        } else {
          Cf[(size_t)row * N + col] = v;
        }
      }
    }
  }
}

// Sum S split-K partials (+optional bias) -> f32 out. N==1024.
__global__ __launch_bounds__(256)
void reduce_kernel(const float* __restrict__ parts, const float* __restrict__ bias,
                   float* __restrict__ out, int S) {
  const int row = blockIdx.x, c4 = threadIdx.x * 4;
  f32x4 a = *(const f32x4*)(parts + (size_t)row * 1024 + c4);
  for (int s = 1; s < S; s++)
    a += *(const f32x4*)(parts + (size_t)s * 2048 * 1024 + (size_t)row * 1024 + c4);
  if (bias) a += *(const f32x4*)(bias + c4);
  *(f32x4*)(out + (size_t)row * 1024 + c4) = a;
}

// ---------------------------------------------------------------------------
// RoPE (head-indexed tables, pos = 1008+h). Q additionally scaled by
// (1/sqrt(DK)) * log2(e) so attention can use exp2 directly on S.
// ---------------------------------------------------------------------------
__global__ __launch_bounds__(256)
void rope_kernel(const float* __restrict__ qkv, bf16_t* __restrict__ Qb,
                 bf16_t* __restrict__ Kb) {
  const int m = blockIdx.x, t = threadIdx.x;
  const int h = t >> 4, i = t & 15;
  const int b = m >> 10, l = m & 1023;
  const float pos = (float)(1008 + h);
  const float ang = pos * exp2f(-0.75f * (float)i);
  float sn, cs;
  sincosf(ang, &sn, &cs);
  const float* q = qkv + (size_t)m * 3072 + h * 64;
  const float* k = q + 1024;
  const size_t ob = ((size_t)(b * 16 + h) * 1024 + l) * 64;
  const float it = 0.125f * 1.44269504088896340736f;  // 1/sqrt(64) * log2(e)
  float qi = q[i], qj = q[i + 16];
  Qb[ob + i]      = (bf16_t)((qi * cs - qj * sn) * it);
  Qb[ob + i + 16] = (bf16_t)((qj * cs + qi * sn) * it);
  Qb[ob + i + 32] = (bf16_t)(q[i + 32] * it);
  Qb[ob + i + 48] = (bf16_t)(q[i + 48] * it);
  float ki = k[i], kj = k[i + 16];
  Kb[ob + i]      = (bf16_t)(ki * cs - kj * sn);
  Kb[ob + i + 16] = (bf16_t)(kj * cs + ki * sn);
  Kb[ob + i + 32] = (bf16_t)k[i + 32];
  Kb[ob + i + 48] = (bf16_t)k[i + 48];
}

// ---------------------------------------------------------------------------
// V transpose: qkv fp32 [2048][3072] -> Vt bf16 [32][64][1024]
// ---------------------------------------------------------------------------
__global__ __launch_bounds__(256)
void vtrans_kernel(const float* __restrict__ qkv, bf16_t* __restrict__ Vt) {
  const int bh = blockIdx.x, lt = blockIdx.y;
  const int b = bh >> 4, h = bh & 15;
  __shared__ float tile[64][65];
  const int t = threadIdx.x;
#pragma unroll
  for (int c = 0; c < 16; c++) {
    int idx = c * 256 + t;
    int r = idx >> 6, d = idx & 63;
    tile[r][d] = qkv[(size_t)(b * 1024 + lt * 64 + r) * 3072 + 2048 + h * 64 + d];
  }
  __syncthreads();
#pragma unroll
  for (int c = 0; c < 16; c++) {
    int idx = c * 256 + t;
    int d = idx >> 6, r = idx & 63;
    Vt[((size_t)bh * 64 + d) * 1024 + lt * 64 + r] = (bf16_t)tile[r][d];
  }
}

// ---------------------------------------------------------------------------
// Attention, 32x32-fragment swapped-operand structure.
// Block = (bh, 64 q-rows), 4 waves: wave = (qt: which 32-q tile, kh: key half).
// Per wave: S^T = mfma(A=K rows, B=Q rows) -> C[col=lane&31 = q][rows = k].
// Lane owns ONE q; softmax reduce = lane-local fmax/sum tree + shfl_xor(32).
// P stays in registers: pack to bf16 words + 4 shfl_xor(32) -> PV B-operand.
// PV: O^T = mfma(A=V^T rows(d), B=P) -> col = q again (per-lane scalar rescale).
// C/D layout: col=lane&31, row=(r&3)+8*(r>>2)+4*(lane>>5)  [m74/m101].
// Key-halves merged through LDS (Olds[d][q] -> conflict-free).
// ---------------------------------------------------------------------------
__global__ __launch_bounds__(256, 2)
void attn_kernel(const bf16_t* __restrict__ Qb, const bf16_t* __restrict__ Kb,
                 const bf16_t* __restrict__ Vt, bf16_t* __restrict__ Ob) {
  const int bh = blockIdx.x;
  const int wave = threadIdx.x >> 6, lane = threadIdx.x & 63;
  const int l31 = lane & 31, hi = lane >> 5;
  const int qt = wave & 1, kh = wave >> 1;
  const int q0 = blockIdx.y * 64 + qt * 32;
  const bf16_t* Q = Qb + (size_t)bh * 65536;
  const bf16_t* K = Kb + (size_t)bh * 65536;
  const bf16_t* V = Vt + (size_t)bh * 65536;

  __shared__ float Olds[2][64][32];
  __shared__ float mlds[2][32], llds[2][32];

  bf16x8 qf[4];
#pragma unroll
  for (int ks = 0; ks < 4; ks++)
    qf[ks] = *(const bf16x8*)(Q + (size_t)(q0 + l31) * 64 + ks * 16 + hi * 8);

  f32x16 o0 = {}, o1 = {};
  float m2 = -1e30f, l2 = 0.0f;

  union U8 { uint32_t w[4]; bf16x8 v; };

  for (int kt = 0; kt < 16; kt++) {
    const int j0 = (kh << 9) + kt * 32;
    f32x16 st = {};
#pragma unroll
    for (int ks = 0; ks < 4; ks++) {
      bf16x8 kf = *(const bf16x8*)(K + (size_t)(j0 + l31) * 64 + ks * 16 + hi * 8);
      st = mfma32(kf, qf[ks], st);
    }
    // lane-local max tree over 16 values + cross-half
    float a0 = fmaxf(st[0], st[1]),  a1 = fmaxf(st[2], st[3]);
    float a2 = fmaxf(st[4], st[5]),  a3 = fmaxf(st[6], st[7]);
    float a4 = fmaxf(st[8], st[9]),  a5 = fmaxf(st[10], st[11]);
    float a6 = fmaxf(st[12], st[13]), a7 = fmaxf(st[14], st[15]);
    float tm = fmaxf(fmaxf(fmaxf(a0, a1), fmaxf(a2, a3)),
                     fmaxf(fmaxf(a4, a5), fmaxf(a6, a7)));
    tm = fmaxf(tm, __shfl_xor(tm, 32));
    // defer-max (T13): rescale only when max grew past threshold
    if (!__all(tm - m2 <= 8.0f)) {
      const float mnew = fmaxf(m2, tm);
      const float c = exp2f(m2 - mnew);
      m2 = mnew;
      l2 *= c;
#pragma unroll
      for (int r = 0; r < 16; r++) { o0[r] *= c; o1[r] *= c; }
    }
    float p[16];
    float ls = 0.0f;
#pragma unroll
    for (int r = 0; r < 16; r++) { p[r] = exp2f(st[r] - m2); ls += p[r]; }
    ls += __shfl_xor(ls, 32);
    l2 += ls;
    // pack p (lane holds k = (r&3)+8*(r>>2)+4*hi) into PV B-fragments
    uint32_t w0 = pkbf(p[0], p[1]),   w1 = pkbf(p[2], p[3]);
    uint32_t w2 = pkbf(p[4], p[5]),   w3 = pkbf(p[6], p[7]);
    uint32_t w4 = pkbf(p[8], p[9]),   w5 = pkbf(p[10], p[11]);
    uint32_t w6 = pkbf(p[12], p[13]), w7 = pkbf(p[14], p[15]);
    uint32_t s0 = (uint32_t)__shfl_xor((int)(hi ? w0 : w2), 32);
    uint32_t s1 = (uint32_t)__shfl_xor((int)(hi ? w1 : w3), 32);
    uint32_t s2 = (uint32_t)__shfl_xor((int)(hi ? w4 : w6), 32);
    uint32_t s3 = (uint32_t)__shfl_xor((int)(hi ? w5 : w7), 32);
    U8 f0, f1;
    f0.w[0] = hi ? s0 : w0;  f0.w[1] = hi ? s1 : w1;
    f0.w[2] = hi ? w2 : s0;  f0.w[3] = hi ? w3 : s1;
    f1.w[0] = hi ? s2 : w4;  f1.w[1] = hi ? s3 : w5;
    f1.w[2] = hi ? w6 : s2;  f1.w[3] = hi ? w7 : s3;
    // PV: O^T += V^T-frag x P-frag  (contraction over 32 keys = 2 mfmas/df)
    const bf16_t* vp0 = V + (size_t)l31 * 1024 + j0 + hi * 8;
    const bf16_t* vp1 = V + (size_t)(32 + l31) * 1024 + j0 + hi * 8;
    o0 = mfma32(*(const bf16x8*)(vp0), f0.v, o0);
    o0 = mfma32(*(const bf16x8*)(vp0 + 16), f1.v, o0);
    o1 = mfma32(*(const bf16x8*)(vp1), f0.v, o1);
    o1 = mfma32(*(const bf16x8*)(vp1 + 16), f1.v, o1);
  }

  if (kh == 1) {
    if (hi == 0) { mlds[qt][l31] = m2; llds[qt][l31] = l2; }
#pragma unroll
    for (int r = 0; r < 16; r++) {
      const int d = (r & 3) + 8 * (r >> 2) + 4 * hi;
      Olds[qt][d][l31] = o0[r];
      Olds[qt][32 + d][l31] = o1[r];
    }
  }
  __syncthreads();
  if (kh == 0) {
    const float pm = mlds[qt][l31], pl = llds[qt][l31];
    const float mn = fmaxf(m2, pm);
    const float ca = exp2f(m2 - mn), cb = exp2f(pm - mn);
    const float inv = 1.0f / (l2 * ca + pl * cb);
    const float fa = ca * inv, fb = cb * inv;
    const int b = bh >> 4, h = bh & 15;
    bf16_t* op = Ob + ((size_t)(b * 1024 + q0 + l31)) * 1024 + h * 64;
#pragma unroll
    for (int rg = 0; rg < 4; rg++) {
      bf16x4 v0, v1;
#pragma unroll
      for (int rr = 0; rr < 4; rr++) {
        const int r = rg * 4 + rr;
        const int d = rr + 8 * rg + 4 * hi;
        v0[rr] = (bf16_t)(o0[r] * fa + Olds[qt][d][l31] * fb);
        v1[rr] = (bf16_t)(o1[r] * fa + Olds[qt][32 + d][l31] * fb);
      }
      *(bf16x4*)(op + 8 * rg + 4 * hi) = v0;
      *(bf16x4*)(op + 32 + 8 * rg + 4 * hi) = v1;
    }
  }
}

// ---------------------------------------------------------------------------
extern "C" void kernel_launch(void* const* d_in, const int* in_sizes, int n_in,
                              void* d_out, int out_size, void* d_ws, size_t ws_size,
                              hipStream_t stream) {
  (void)in_sizes; (void)n_in; (void)out_size;
  const float* src  = (const float*)d_in[0];
  const float* Wq   = (const float*)d_in[1];
  const float* Wk   = (const float*)d_in[2];
  const float* Wv   = (const float*)d_in[3];
  const float* Wo   = (const float*)d_in[4];
  const float* ln1g = (const float*)d_in[5];
  const float* ln1b = (const float*)d_in[6];
  const float* W1   = (const float*)d_in[7];
  const float* b1   = (const float*)d_in[8];
  const float* W2   = (const float*)d_in[9];
  const float* b2   = (const float*)d_in[10];
  const float* ln2g = (const float*)d_in[11];
  const float* ln2b = (const float*)d_in[12];
  const float* ln0g = (const float*)d_in[13];
  const float* ln0b = (const float*)d_in[14];

  char* ws = (char*)d_ws;
  size_t off = 0;
  auto alloc = [&](size_t bytes) -> char* {
    char* p = ws + off;
    off += (bytes + 255) & ~(size_t)255;
    return p;
  };
  bf16_t* wqkvt = (bf16_t*)alloc((size_t)3072 * 1024 * 2);
  bf16_t* wot   = (bf16_t*)alloc((size_t)1024 * 1024 * 2);
  bf16_t* w1t   = (bf16_t*)alloc((size_t)4096 * 1024 * 2);
  bf16_t* w2t   = (bf16_t*)alloc((size_t)1024 * 4096 * 2);
  float*  x     = (float*) alloc((size_t)2048 * 1024 * 4);
  bf16_t* xb    = (bf16_t*)alloc((size_t)2048 * 1024 * 2);
  float*  x1    = (float*) alloc((size_t)2048 * 1024 * 4);
  bf16_t* x1b   = (bf16_t*)alloc((size_t)2048 * 1024 * 2);
  float*  t0    = (float*) alloc((size_t)2048 * 1024 * 4);
  char*   R     = alloc((size_t)48 * 1024 * 1024);
  // Phase-1 views of R (QKV -> attention):
  float*  qkv   = (float*)R;                                      // 24 MB
  bf16_t* Qbuf  = (bf16_t*)(R + (size_t)24 * 1024 * 1024);        //  4 MB
  bf16_t* Kbuf  = (bf16_t*)(R + (size_t)28 * 1024 * 1024);        //  4 MB
  bf16_t* Vt    = (bf16_t*)(R + (size_t)32 * 1024 * 1024);        //  4 MB
  bf16_t* Ob    = (bf16_t*)(R + (size_t)36 * 1024 * 1024);        //  4 MB
  // Phase-2 views of R (post-attention):
  float*  parts = (float*)R;                                      // up to 32 MB
  bf16_t* hb    = (bf16_t*)(R + (size_t)32 * 1024 * 1024);        // 16 MB
  if (off > ws_size) return;

  ln_kernel<<<2048, 256, 0, stream>>>(src, nullptr, ln0g, ln0b, 32.0f, x, xb);

  for (int l = 0; l < 4; l++) {
    const float* wq = Wq + (size_t)l * 1024 * 1024;
    const float* wk = Wk + (size_t)l * 1024 * 1024;
    const float* wv = Wv + (size_t)l * 1024 * 1024;
    const float* wo = Wo + (size_t)l * 1024 * 1024;
    const float* w1 = W1 + (size_t)l * 1024 * 4096;
    const float* w2 = W2 + (size_t)l * 4096 * 1024;

    conv4_kernel<<<dim3(16, 16, 4), 256, 0, stream>>>(
        wq, wk, wv, wo, wqkvt, wqkvt + (size_t)1024 * 1024,
        wqkvt + (size_t)2048 * 1024, wot);
    conv_t_kernel<<<dim3(16, 64), 256, 0, stream>>>(w1, w1t, 1024, 4096);
    conv_t_kernel<<<dim3(64, 16), 256, 0, stream>>>(w2, w2t, 4096, 1024);

    gemm128<0><<<dim3(16, 24, 1), 256, 0, stream>>>(xb, wqkvt, nullptr, qkv, nullptr,
                                                    3072, 1024, 1024);
    rope_kernel<<<2048, 256, 0, stream>>>(qkv, Qbuf, Kbuf);
    vtrans_kernel<<<dim3(32, 16), 256, 0, stream>>>(qkv, Vt);
    attn_kernel<<<dim3(32, 16), 256, 0, stream>>>(Qbuf, Kbuf, Vt, Ob);

    gemm128<3><<<dim3(16, 8, 2), 256, 0, stream>>>(Ob, wot, nullptr, parts, nullptr,
                                                   1024, 1024, 512);
    reduce_kernel<<<2048, 256, 0, stream>>>(parts, nullptr, t0, 2);
    ln_kernel<<<2048, 256, 0, stream>>>(t0, x, ln1g + (size_t)l * 1024,
                                        ln1b + (size_t)l * 1024, 1.0f, x1, x1b);

    gemm128<1><<<dim3(16, 32, 1), 256, 0, stream>>>(x1b, w1t, b1 + (size_t)l * 4096,
                                                    nullptr, hb, 4096, 1024, 1024);
    gemm128<3><<<dim3(16, 8, 4), 256, 0, stream>>>(hb, w2t, nullptr, parts, nullptr,
                                                   1024, 4096, 1024);
    reduce_kernel<<<2048, 256, 0, stream>>>(parts, b2 + (size_t)l * 1024, t0, 4);

    const bool last = (l == 3);
    ln_kernel<<<2048, 256, 0, stream>>>(t0, x1, ln2g + (size_t)l * 1024,
                                        ln2b + (size_t)l * 1024, 1.0f,
                                        last ? (float*)d_out : x,
                                        last ? nullptr : xb);
  }
}